// Round 6
// baseline (108.671 us; speedup 1.0000x reference)
//
#include <hip/hip_runtime.h>
#include <math.h>

// Problem constants
#define Bb   8
#define Dd   256
#define Tt   500
#define SPK  2000
#define SPKP 2048
#define BN   16       // B*N
#define L2E  1.4426950408889634f
#define LN2  0.6931471805599453f

#define EXP2F(x) __builtin_amdgcn_exp2f(x)
#define LOG2F(x) __builtin_amdgcn_logf(x)

// ---- ws layout (float offsets unless noted) ----
#define F_ESN   0                      // -alpha*||E_s||^2*log2e, pad=-1e30  [2048]
#define F_HSQP  4096                   // hsq partials [16][512][4]            (ends 36864)
#define F_PM    36864                  // partial m (log2 dom) [16*512][8]     (ends 102400)
#define F_PL    102400                 // partial l [16*512][8]                (ends 167936)
#define F_DMP2  167936                 // dmin partials [16][512][4 dchunk][2] (ends 233472)
#define EBF_BYTES ((size_t)233472 * 4)            // bf16 E [2048][256]  (1 MB)
#define HBF_BYTES (EBF_BYTES + (size_t)1048576)   // bf16 H^T [16][512][256] (4.2 MB)

// LDS geometry for lse kernel
#define ROWSTRIDE 264                  // bf16 elems per row (padded)

typedef __bf16 v8bf __attribute__((ext_vector_type(8)));
typedef float  v4f  __attribute__((ext_vector_type(4)));

__device__ inline unsigned pack_bf16x2(float lo, float hi) {
    union { __bf16 h; unsigned short u; } a, b;
    a.h = (__bf16)lo; b.h = (__bf16)hi;
    return ((unsigned)b.u << 16) | (unsigned)a.u;
}

// ================= kernel 1: prep_all =================
// blocks 0..511    : E -> bf16 + esn
// blocks 512..527  : gather out
// blocks 528..1551 : H transpose -> hbf bf16 [bn][t][k] + hsq partials
//                    + fused dmin partials
__global__ __launch_bounds__(256) void prep_all_kernel(
        const float* __restrict__ E, const int* __restrict__ S,
        const float* __restrict__ H, const float* __restrict__ alpha,
        const float* __restrict__ beta, float* __restrict__ ws,
        float* __restrict__ out) {
    int bid = blockIdx.x;
    int tid = threadIdx.x;

    if (bid < 512) {
        int s = bid * 4 + (tid >> 6);
        int lane = tid & 63;
        float4 v = make_float4(0.f, 0.f, 0.f, 0.f);
        if (s < SPK) v = ((const float4*)E)[s * 64 + lane];
        __bf16* ebf = (__bf16*)((char*)ws + EBF_BYTES);
        uint2 pp;
        pp.x = pack_bf16x2(v.x, v.y);
        pp.y = pack_bf16x2(v.z, v.w);
        *(uint2*)(ebf + (size_t)s * Dd + lane * 4) = pp;
        float acc = v.x * v.x + v.y * v.y + v.z * v.z + v.w * v.w;
        #pragma unroll
        for (int off = 32; off > 0; off >>= 1) acc += __shfl_down(acc, off, 64);
        if (lane == 0) ws[F_ESN + s] = (s < SPK) ? (-alpha[0] * acc * L2E) : -1e30f;
    } else if (bid < 528) {
        int i = (bid - 512) * 256 + tid;
        int bn = i >> 8, d = i & 255;
        out[i] = E[(size_t)S[bn * Tt] * Dd + d];
    } else {
        // ---- H transpose tile: (bn, 32 t) x (64 d), + fused dmin partials ----
        __shared__ float trans[32][65];
        int u = bid - 528;                 // 0..1023
        int bn = u >> 6;
        int r = u & 63;
        int tt0 = (r & 15) * 32;
        int d0 = (r >> 4) * 64;
        const float* Hb = H + (size_t)bn * Dd * Tt;
        #pragma unroll
        for (int p = 0; p < 8; ++p) {
            int flat = p * 256 + tid;      // 0..2047
            int dd = flat >> 5;            // 0..63
            int tl = flat & 31;
            int t = tt0 + tl;
            trans[tl][dd] = (t < Tt) ? Hb[(size_t)(d0 + dd) * Tt + t] : 0.f;
        }
        __syncthreads();
        int tw = tid >> 3;                 // 0..31  (t-row)
        int j = tid & 7;                   // 8 d's each
        int t = tt0 + tw;
        bool ok = (t < Tt);
        int tc = ok ? t : (Tt - 1);
        int b = bn >> 1;
        int s0 = S[(b * 2 + 0) * Tt + tc];
        int s1 = S[(b * 2 + 1) * Tt + tc];
        const float4* e0p = (const float4*)(E + (size_t)s0 * Dd + d0 + j * 8);
        const float4* e1p = (const float4*)(E + (size_t)s1 * Dd + d0 + j * 8);
        float4 ea0 = e0p[0], ea1 = e0p[1];
        float4 eb0 = e1p[0], eb1 = e1p[1];
        float ev0[8] = {ea0.x, ea0.y, ea0.z, ea0.w, ea1.x, ea1.y, ea1.z, ea1.w};
        float ev1[8] = {eb0.x, eb0.y, eb0.z, eb0.w, eb1.x, eb1.y, eb1.z, eb1.w};
        float sq = 0.f, p0 = 0.f, p1 = 0.f;
        float vals[8];
        #pragma unroll
        for (int e = 0; e < 8; ++e) {
            float x = trans[tw][j * 8 + e];
            vals[e] = x;
            sq = fmaf(x, x, sq);
            float u0 = x - ev0[e]; p0 = fmaf(u0, u0, p0);
            float u1 = x - ev1[e]; p1 = fmaf(u1, u1, p1);
        }
        sq += __shfl_xor(sq, 1, 64); p0 += __shfl_xor(p0, 1, 64); p1 += __shfl_xor(p1, 1, 64);
        sq += __shfl_xor(sq, 2, 64); p0 += __shfl_xor(p0, 2, 64); p1 += __shfl_xor(p1, 2, 64);
        sq += __shfl_xor(sq, 4, 64); p0 += __shfl_xor(p0, 4, 64); p1 += __shfl_xor(p1, 4, 64);
        uint4 pk;
        pk.x = pack_bf16x2(vals[0], vals[1]);
        pk.y = pack_bf16x2(vals[2], vals[3]);
        pk.z = pack_bf16x2(vals[4], vals[5]);
        pk.w = pack_bf16x2(vals[6], vals[7]);
        __bf16* hbf = (__bf16*)((char*)ws + HBF_BYTES);
        *(uint4*)(hbf + ((size_t)(bn * 512 + t) * Dd + d0 + j * 8)) = pk;
        if (j == 0) {
            ws[F_HSQP + (size_t)(bn * 512 + t) * 4 + (r >> 4)] = sq;
            if (ok) {
                float2 pr = make_float2(p0, p1);
                *(float2*)(ws + F_DMP2 + (((size_t)bn * 512 + t) * 4 + (r >> 4)) * 2) = pr;
            }
        }
    }
}

// ================= kernel 2: MFMA lse =================
// grid (bn=16, ttile=8 [64 t], mz=8 [256 spk]); 256 thr = 4 waves.
// v6: only B tile in LDS (33.8 KB -> 4 blocks/CU). bq fragments re-read from
// LDS inside the ks-loop (cheap, proven r0); A fragments read DIRECTLY from
// L2-resident ebf per wave; ZERO barriers in the main loop. Occupancy does the
// latency hiding (target ~16 waves/CU vs previous 8).
__global__ __launch_bounds__(256, 2) void lse_mfma_kernel(
        const float* __restrict__ alpha, const float* __restrict__ beta,
        float* __restrict__ ws) {
    __shared__ __bf16 shB[64 * ROWSTRIDE];     // H^T tile [t][k]
    __shared__ float mrg_m[4][4][16], mrg_l[4][4][16];

    int bn = blockIdx.x;
    int t0 = blockIdx.y * 64;
    int mz = blockIdx.z;                       // 0..7, 256 speakers each
    int tid = threadIdx.x;
    int lane = tid & 63;
    int n = lane & 15;
    int q = lane >> 4;
    int w = tid >> 6;

    const __bf16* ebf = (const __bf16*)((const char*)ws + EBF_BYTES);
    const __bf16* hbf = (const __bf16*)((const char*)ws + HBF_BYTES);

    // ---- stage B tile (64 t x 256 k): coalesced uint4 -> LDS (once) ----
    #pragma unroll
    for (int p = 0; p < 8; ++p) {
        int flat = p * 256 + tid;          // 0..2047
        int row = flat >> 5;               // 0..63
        int ch = flat & 31;                // 16-B chunk
        uint4 vb = *(const uint4*)(hbf + ((size_t)(bn * 512 + t0 + row) * Dd + ch * 8));
        *(uint4*)(shB + row * ROWSTRIDE + ch * 8) = vb;
    }
    __syncthreads();                       // shB is read-only hereafter

    float A = alpha[0], Bv = beta[0];
    float ta2p = 2.f * A * L2E;
    float ctc2[4];
    #pragma unroll
    for (int i = 0; i < 4; ++i) {
        int t = t0 + 16 * i + n;
        float4 hq = *(const float4*)(ws + F_HSQP + (size_t)(bn * 512 + t) * 4);
        float hs = hq.x + hq.y + hq.z + hq.w;
        ctc2[i] = (t < Tt) ? ((Bv - A * hs) * L2E) : 0.f;
    }

    float lm[4], ll[4];
    #pragma unroll
    for (int i = 0; i < 4; ++i) { lm[i] = -INFINITY; ll[i] = 0.f; }

    // this lane's A-row base (speaker row of chunk 0) and esn base
    const __bf16* ap = ebf + ((size_t)(mz * 256 + w * 16 + n) * Dd) + q * 8;
    const float* esb = ws + F_ESN + mz * 256 + w * 16 + q * 4;

    for (int c = 0; c < 4; ++c) {
        // A fragments straight from L2 (no LDS, no barrier)
        v8bf af[8];
        #pragma unroll
        for (int ks = 0; ks < 8; ++ks) {
            af[ks] = *reinterpret_cast<const v8bf*>(ap + (size_t)c * 64 * Dd + ks * 32);
        }
        float4 es4 = *(const float4*)(esb + c * 64);

        v4f acc[4];
        #pragma unroll
        for (int i = 0; i < 4; ++i) acc[i] = (v4f){0.f, 0.f, 0.f, 0.f};
        #pragma unroll
        for (int ks = 0; ks < 8; ++ks) {
            #pragma unroll
            for (int i = 0; i < 4; ++i) {
                v8bf bqv = *reinterpret_cast<const v8bf*>(
                    &shB[(16 * i + n) * ROWSTRIDE + ks * 32 + q * 8]);
                acc[i] = __builtin_amdgcn_mfma_f32_16x16x32_bf16(af[ks], bqv, acc[i], 0, 0, 0);
            }
        }
        float e0 = es4.x, e1 = es4.y, e2 = es4.z, e3 = es4.w;
        #pragma unroll
        for (int i = 0; i < 4; ++i) {
            float c2 = ctc2[i];
            float v0 = fmaf(ta2p, acc[i][0], c2 + e0);
            float v1 = fmaf(ta2p, acc[i][1], c2 + e1);
            float v2 = fmaf(ta2p, acc[i][2], c2 + e2);
            float v3 = fmaf(ta2p, acc[i][3], c2 + e3);
            float vm = fmaxf(fmaxf(v0, v1), fmaxf(v2, v3));
            float s = EXP2F(v0 - vm) + EXP2F(v1 - vm) + EXP2F(v2 - vm) + EXP2F(v3 - vm);
            float nm = fmaxf(lm[i], vm);
            ll[i] = ll[i] * EXP2F(lm[i] - nm) + s * EXP2F(vm - nm);
            lm[i] = nm;
        }
    }

    // ---- merge quads within wave (t = n repeats across q) ----
    #pragma unroll
    for (int i = 0; i < 4; ++i) {
        float m = lm[i], l = ll[i];
        #pragma unroll
        for (int msk = 16; msk <= 32; msk <<= 1) {
            float om = __shfl_xor(m, msk, 64);
            float ol = __shfl_xor(l, msk, 64);
            float nm = fmaxf(m, om);
            l = l * EXP2F(m - nm) + ol * EXP2F(om - nm);
            m = nm;
        }
        if (q == 0) { mrg_m[w][i][n] = m; mrg_l[w][i][n] = l; }
    }
    __syncthreads();

    // ---- merge waves (different speakers), write partials per (bn,t,mz) ----
    if (tid < 64) {
        int i = tid >> 4, cc = tid & 15;
        float m = mrg_m[0][i][cc], l = mrg_l[0][i][cc];
        #pragma unroll
        for (int wv = 1; wv < 4; ++wv) {
            float om = mrg_m[wv][i][cc], ol = mrg_l[wv][i][cc];
            float nm = fmaxf(m, om);
            l = l * EXP2F(m - nm) + ol * EXP2F(om - nm);
            m = nm;
        }
        int tw = t0 + 16 * i + cc;
        if (tw < Tt) {
            ws[F_PM + ((size_t)(bn * 512 + tw)) * 8 + mz] = m;
            ws[F_PL + ((size_t)(bn * 512 + tw)) * 8 + mz] = l;
        }
    }
}

// ================= kernel 3: final combine =================
__global__ __launch_bounds__(1024) void final_kernel(
        const float* __restrict__ alpha, const float* __restrict__ beta,
        const float* __restrict__ ws, float* __restrict__ out) {
    __shared__ float rL[16], rD[16];
    int tid = threadIdx.x;
    float A = alpha[0], Bv = beta[0];

    float lsum = 0.f;
    #pragma unroll
    for (int it = 0; it < 8; ++it) {
        int idx = it * 1024 + tid;         // bn*512 + t
        int t = idx & 511;
        if (t < Tt) {
            const float4* M = (const float4*)(ws + F_PM + (size_t)idx * 8);
            const float4* L = (const float4*)(ws + F_PL + (size_t)idx * 8);
            float4 m4 = M[0], m5 = M[1];
            float4 l4 = L[0], l5 = L[1];
            float m = m4.x, l = l4.x, nm;
            nm = fmaxf(m, m4.y); l = l * EXP2F(m - nm) + l4.y * EXP2F(m4.y - nm); m = nm;
            nm = fmaxf(m, m4.z); l = l * EXP2F(m - nm) + l4.z * EXP2F(m4.z - nm); m = nm;
            nm = fmaxf(m, m4.w); l = l * EXP2F(m - nm) + l4.w * EXP2F(m4.w - nm); m = nm;
            nm = fmaxf(m, m5.x); l = l * EXP2F(m - nm) + l5.x * EXP2F(m5.x - nm); m = nm;
            nm = fmaxf(m, m5.y); l = l * EXP2F(m - nm) + l5.y * EXP2F(m5.y - nm); m = nm;
            nm = fmaxf(m, m5.z); l = l * EXP2F(m - nm) + l5.z * EXP2F(m5.z - nm); m = nm;
            nm = fmaxf(m, m5.w); l = l * EXP2F(m - nm) + l5.w * EXP2F(m5.w - nm); m = nm;
            lsum += LN2 * (m + LOG2F(l));
        }
    }

    float dsum = 0.f;
    #pragma unroll
    for (int it = 0; it < 4; ++it) {
        int idx = it * 1024 + tid;         // 0..4095 : b = idx>>9, t = idx&511
        int t = idx & 511;
        if (t < Tt) {
            int b = idx >> 9;
            const float4* P0 = (const float4*)(ws + F_DMP2 + ((size_t)(2 * b + 0) * 512 + t) * 8);
            const float4* P1 = (const float4*)(ws + F_DMP2 + ((size_t)(2 * b + 1) * 512 + t) * 8);
            float4 a0 = P0[0], a1 = P0[1];
            float4 b0 = P1[0], b1 = P1[1];
            float d00 = a0.x + a0.z + a1.x + a1.z;
            float d01 = a0.y + a0.w + a1.y + a1.w;
            float d10 = b0.x + b0.z + b1.x + b1.z;
            float d11 = b0.y + b0.w + b1.y + b1.w;
            float dm = fminf(d00 + d11, d01 + d10);
            dsum += -A * dm + Bv;
        }
    }

    int lane = tid & 63, w = tid >> 6;
    #pragma unroll
    for (int off = 32; off > 0; off >>= 1) {
        lsum += __shfl_down(lsum, off, 64);
        dsum += __shfl_down(dsum, off, 64);
    }
    if (lane == 0) { rL[w] = lsum; rD[w] = dsum; }
    __syncthreads();
    if (tid == 0) {
        float L = 0.f, D = 0.f;
        #pragma unroll
        for (int wv = 0; wv < 16; ++wv) { L += rL[wv]; D += rD[wv]; }
        out[BN * Dd] = -(D / (float)(Bb * Tt)) + L / (float)(BN * Tt);
    }
}

extern "C" void kernel_launch(void* const* d_in, const int* in_sizes, int n_in,
                              void* d_out, int out_size, void* d_ws, size_t ws_size,
                              hipStream_t stream) {
    const float* H     = (const float*)d_in[0];
    const int*   S     = (const int*)d_in[1];
    const float* E     = (const float*)d_in[2];
    const float* alpha = (const float*)d_in[3];
    const float* beta  = (const float*)d_in[4];
    float* out = (float*)d_out;
    float* ws  = (float*)d_ws;

    prep_all_kernel<<<1552, 256, 0, stream>>>(E, S, H, alpha, beta, ws, out);
    lse_mfma_kernel<<<dim3(BN, 8, 8), 256, 0, stream>>>(alpha, beta, ws);
    final_kernel<<<1, 1024, 0, stream>>>(alpha, beta, ws, out);
}

// Round 7
// 93.202 us; speedup vs baseline: 1.1660x; 1.1660x over previous
//
#include <hip/hip_runtime.h>
#include <math.h>

// Problem constants
#define Bb   8
#define Dd   256
#define Tt   500
#define SPK  2000
#define SPKP 2048
#define BN   16       // B*N
#define L2E  1.4426950408889634f
#define LN2  0.6931471805599453f

#define EXP2F(x) __builtin_amdgcn_exp2f(x)
#define LOG2F(x) __builtin_amdgcn_logf(x)

// ---- ws layout (float offsets, r4 map) ----
#define F_ESN   0                      // -alpha*||E_s||^2*log2e, pad=-1e30  [2048]
#define F_HSQP  4096                   // hsq partials [16][512][4]            (ends 36864)
#define F_PM    36864                  // partial m (log2 dom) [16*512][4]     (ends 69632)
#define F_PL    69632                  // partial l [16*512][4]                (ends 102400)
#define F_DMP2  102400                 // dmin partials [16][512][4 dchunk][2] (ends 167936)
#define EBF_BYTES ((size_t)167936 * 4)            // bf16 E [2048][256]  (1 MB)
#define HBF_BYTES (EBF_BYTES + (size_t)1048576)   // bf16 H^T [16][512][256] (4.2 MB)

// LDS geometry for lse kernel
#define ROWSTRIDE 264                  // bf16 elems per row (padded; proven-cheap banks)

typedef __bf16 v8bf __attribute__((ext_vector_type(8)));
typedef float  v4f  __attribute__((ext_vector_type(4)));

__device__ inline unsigned pack_bf16x2(float lo, float hi) {
    union { __bf16 h; unsigned short u; } a, b;
    a.h = (__bf16)lo; b.h = (__bf16)hi;
    return ((unsigned)b.u << 16) | (unsigned)a.u;
}

// ================= kernel 1: prep_all =================
// blocks 0..511    : E -> bf16 + esn
// blocks 512..527  : gather out (+ zero loss slot)
// blocks 528..1551 : H transpose -> hbf bf16 [bn][t][k] + hsq partials
//                    + fused dmin partials
__global__ __launch_bounds__(256) void prep_all_kernel(
        const float* __restrict__ E, const int* __restrict__ S,
        const float* __restrict__ H, const float* __restrict__ alpha,
        const float* __restrict__ beta, float* __restrict__ ws,
        float* __restrict__ out) {
    int bid = blockIdx.x;
    int tid = threadIdx.x;

    if (bid < 512) {
        int s = bid * 4 + (tid >> 6);
        int lane = tid & 63;
        float4 v = make_float4(0.f, 0.f, 0.f, 0.f);
        if (s < SPK) v = ((const float4*)E)[s * 64 + lane];
        __bf16* ebf = (__bf16*)((char*)ws + EBF_BYTES);
        uint2 pp;
        pp.x = pack_bf16x2(v.x, v.y);
        pp.y = pack_bf16x2(v.z, v.w);
        *(uint2*)(ebf + (size_t)s * Dd + lane * 4) = pp;
        float acc = v.x * v.x + v.y * v.y + v.z * v.z + v.w * v.w;
        #pragma unroll
        for (int off = 32; off > 0; off >>= 1) acc += __shfl_down(acc, off, 64);
        if (lane == 0) ws[F_ESN + s] = (s < SPK) ? (-alpha[0] * acc * L2E) : -1e30f;
    } else if (bid < 528) {
        if (bid == 512 && tid == 0) out[BN * Dd] = 0.f;   // zero loss slot for final atomics
        int i = (bid - 512) * 256 + tid;
        int bn = i >> 8, d = i & 255;
        out[i] = E[(size_t)S[bn * Tt] * Dd + d];
    } else {
        // ---- H transpose tile: (bn, 32 t) x (64 d), + fused dmin partials ----
        __shared__ float trans[32][65];
        int u = bid - 528;                 // 0..1023
        int bn = u >> 6;
        int r = u & 63;
        int tt0 = (r & 15) * 32;
        int d0 = (r >> 4) * 64;
        const float* Hb = H + (size_t)bn * Dd * Tt;
        #pragma unroll
        for (int p = 0; p < 8; ++p) {
            int flat = p * 256 + tid;      // 0..2047
            int dd = flat >> 5;            // 0..63
            int tl = flat & 31;
            int t = tt0 + tl;
            trans[tl][dd] = (t < Tt) ? Hb[(size_t)(d0 + dd) * Tt + t] : 0.f;
        }
        __syncthreads();
        int tw = tid >> 3;                 // 0..31  (t-row)
        int j = tid & 7;                   // 8 d's each
        int t = tt0 + tw;
        bool ok = (t < Tt);
        int tc = ok ? t : (Tt - 1);
        int b = bn >> 1;
        int s0 = S[(b * 2 + 0) * Tt + tc];
        int s1 = S[(b * 2 + 1) * Tt + tc];
        const float4* e0p = (const float4*)(E + (size_t)s0 * Dd + d0 + j * 8);
        const float4* e1p = (const float4*)(E + (size_t)s1 * Dd + d0 + j * 8);
        float4 ea0 = e0p[0], ea1 = e0p[1];
        float4 eb0 = e1p[0], eb1 = e1p[1];
        float ev0[8] = {ea0.x, ea0.y, ea0.z, ea0.w, ea1.x, ea1.y, ea1.z, ea1.w};
        float ev1[8] = {eb0.x, eb0.y, eb0.z, eb0.w, eb1.x, eb1.y, eb1.z, eb1.w};
        float sq = 0.f, p0 = 0.f, p1 = 0.f;
        float vals[8];
        #pragma unroll
        for (int e = 0; e < 8; ++e) {
            float x = trans[tw][j * 8 + e];
            vals[e] = x;
            sq = fmaf(x, x, sq);
            float u0 = x - ev0[e]; p0 = fmaf(u0, u0, p0);
            float u1 = x - ev1[e]; p1 = fmaf(u1, u1, p1);
        }
        sq += __shfl_xor(sq, 1, 64); p0 += __shfl_xor(p0, 1, 64); p1 += __shfl_xor(p1, 1, 64);
        sq += __shfl_xor(sq, 2, 64); p0 += __shfl_xor(p0, 2, 64); p1 += __shfl_xor(p1, 2, 64);
        sq += __shfl_xor(sq, 4, 64); p0 += __shfl_xor(p0, 4, 64); p1 += __shfl_xor(p1, 4, 64);
        uint4 pk;
        pk.x = pack_bf16x2(vals[0], vals[1]);
        pk.y = pack_bf16x2(vals[2], vals[3]);
        pk.z = pack_bf16x2(vals[4], vals[5]);
        pk.w = pack_bf16x2(vals[6], vals[7]);
        __bf16* hbf = (__bf16*)((char*)ws + HBF_BYTES);
        *(uint4*)(hbf + ((size_t)(bn * 512 + t) * Dd + d0 + j * 8)) = pk;
        if (j == 0) {
            ws[F_HSQP + (size_t)(bn * 512 + t) * 4 + (r >> 4)] = sq;
            if (ok) {
                float2 pr = make_float2(p0, p1);
                *(float2*)(ws + F_DMP2 + (((size_t)bn * 512 + t) * 4 + (r >> 4)) * 2) = pr;
            }
        }
    }
}

// ================= kernel 2: MFMA lse =================
// grid (bn=16, ttile=8 [64 t], mz=4 [512 spk]); 256 thr = 4 waves.
// v7: per-wave PRIVATE A-staging: each wave stages its own 16 speaker rows
// (coalesced 512-B segments) into its own LDS region -> ZERO barriers in the
// main loop (intra-wave lgkmcnt ordering only). bq resident; shB read-only
// after one barrier. Waves desync and hide each other's L2 latency.
__global__ __launch_bounds__(256, 2) void lse_mfma_kernel(
        const float* __restrict__ alpha, const float* __restrict__ beta,
        float* __restrict__ ws) {
    __shared__ __bf16 shB[64 * ROWSTRIDE];          // H^T tile [t][k]
    __shared__ __bf16 shA[4 * 16 * ROWSTRIDE];      // per-wave 16-row A regions
    __shared__ float mrg_m[4][4][16], mrg_l[4][4][16];

    int bn = blockIdx.x;
    int t0 = blockIdx.y * 64;
    int mz = blockIdx.z;
    int tid = threadIdx.x;
    int lane = tid & 63;
    int n = lane & 15;
    int q = lane >> 4;
    int w = tid >> 6;

    const __bf16* ebf = (const __bf16*)((const char*)ws + EBF_BYTES);
    const __bf16* hbf = (const __bf16*)((const char*)ws + HBF_BYTES);

    // ---- stage B tile (64 t x 256 k): coalesced uint4 -> LDS (once) ----
    #pragma unroll
    for (int p = 0; p < 8; ++p) {
        int flat = p * 256 + tid;          // 0..2047
        int row = flat >> 5;               // 0..63
        int ch = flat & 31;                // 16-B chunk
        uint4 vb = *(const uint4*)(hbf + ((size_t)(bn * 512 + t0 + row) * Dd + ch * 8));
        *(uint4*)(shB + row * ROWSTRIDE + ch * 8) = vb;
    }
    __syncthreads();                       // shB read-only hereafter

    // ---- B fragments resident in registers ----
    v8bf bq[4][8];
    #pragma unroll
    for (int i = 0; i < 4; ++i) {
        int tloc = 16 * i + n;
        #pragma unroll
        for (int ks = 0; ks < 8; ++ks) {
            bq[i][ks] = *reinterpret_cast<const v8bf*>(&shB[tloc * ROWSTRIDE + ks * 32 + q * 8]);
        }
    }

    float A = alpha[0], Bv = beta[0];
    float ta2p = 2.f * A * L2E;
    float ctc2[4];
    #pragma unroll
    for (int i = 0; i < 4; ++i) {
        int t = t0 + 16 * i + n;
        float4 hq = *(const float4*)(ws + F_HSQP + (size_t)(bn * 512 + t) * 4);
        float hs = hq.x + hq.y + hq.z + hq.w;
        ctc2[i] = (t < Tt) ? ((Bv - A * hs) * L2E) : 0.f;
    }

    float lm[4], ll[4];
    #pragma unroll
    for (int i = 0; i < 4; ++i) { lm[i] = -INFINITY; ll[i] = 0.f; }

    __bf16* shAw = shA + w * (16 * ROWSTRIDE);      // this wave's private region

    for (int c = 0; c < 8; ++c) {
        int sbase = mz * 512 + c * 64 + w * 16;     // this wave's 16 rows

        // coalesced load (2x512-B segments per instruction), then LDS write.
        uint4 tmp[8];
        #pragma unroll
        for (int p = 0; p < 8; ++p) {
            int flat = p * 64 + lane;      // 0..511
            int row = flat >> 5;           // 0..15
            int ch = flat & 31;
            tmp[p] = *(const uint4*)(ebf + ((size_t)(sbase + row) * Dd + ch * 8));
        }
        #pragma unroll
        for (int p = 0; p < 8; ++p) {
            int flat = p * 64 + lane;
            int row = flat >> 5;
            int ch = flat & 31;
            *(uint4*)(shAw + row * ROWSTRIDE + ch * 8) = tmp[p];
        }
        __asm__ volatile("s_waitcnt lgkmcnt(0)" ::: "memory");  // intra-wave: writes done

        v8bf af[8];
        #pragma unroll
        for (int ks = 0; ks < 8; ++ks) {
            af[ks] = *reinterpret_cast<const v8bf*>(&shAw[n * ROWSTRIDE + ks * 32 + q * 8]);
        }
        float4 es4 = *(const float4*)(ws + F_ESN + sbase - w * 16 + w * 16 + q * 4);

        v4f acc[4];
        #pragma unroll
        for (int i = 0; i < 4; ++i) acc[i] = (v4f){0.f, 0.f, 0.f, 0.f};
        #pragma unroll
        for (int ks = 0; ks < 8; ++ks) {
            #pragma unroll
            for (int i = 0; i < 4; ++i) {
                acc[i] = __builtin_amdgcn_mfma_f32_16x16x32_bf16(af[ks], bq[i][ks], acc[i], 0, 0, 0);
            }
        }
        float e0 = es4.x, e1 = es4.y, e2 = es4.z, e3 = es4.w;
        #pragma unroll
        for (int i = 0; i < 4; ++i) {
            float c2 = ctc2[i];
            float v0 = fmaf(ta2p, acc[i][0], c2 + e0);
            float v1 = fmaf(ta2p, acc[i][1], c2 + e1);
            float v2 = fmaf(ta2p, acc[i][2], c2 + e2);
            float v3 = fmaf(ta2p, acc[i][3], c2 + e3);
            float vm = fmaxf(fmaxf(v0, v1), fmaxf(v2, v3));
            float s = EXP2F(v0 - vm) + EXP2F(v1 - vm) + EXP2F(v2 - vm) + EXP2F(v3 - vm);
            float nm = fmaxf(lm[i], vm);
            ll[i] = ll[i] * EXP2F(lm[i] - nm) + s * EXP2F(vm - nm);
            lm[i] = nm;
        }
    }

    // ---- merge quads within wave (t = n repeats across q) ----
    #pragma unroll
    for (int i = 0; i < 4; ++i) {
        float m = lm[i], l = ll[i];
        #pragma unroll
        for (int msk = 16; msk <= 32; msk <<= 1) {
            float om = __shfl_xor(m, msk, 64);
            float ol = __shfl_xor(l, msk, 64);
            float nm = fmaxf(m, om);
            l = l * EXP2F(m - nm) + ol * EXP2F(om - nm);
            m = nm;
        }
        if (q == 0) { mrg_m[w][i][n] = m; mrg_l[w][i][n] = l; }
    }
    __syncthreads();

    // ---- merge waves (different speakers), write partials per (bn,t,mz) ----
    if (tid < 64) {
        int i = tid >> 4, cc = tid & 15;
        float m = mrg_m[0][i][cc], l = mrg_l[0][i][cc];
        #pragma unroll
        for (int wv = 1; wv < 4; ++wv) {
            float om = mrg_m[wv][i][cc], ol = mrg_l[wv][i][cc];
            float nm = fmaxf(m, om);
            l = l * EXP2F(m - nm) + ol * EXP2F(om - nm);
            m = nm;
        }
        int tw = t0 + 16 * i + cc;
        if (tw < Tt) {
            ws[F_PM + (bn * 512 + tw) * 4 + mz] = m;
            ws[F_PL + (bn * 512 + tw) * 4 + mz] = l;
        }
    }
}

// ================= kernel 3: final combine (8 blocks, atomic) =================
__global__ __launch_bounds__(512) void final_kernel(
        const float* __restrict__ alpha, const float* __restrict__ beta,
        const float* __restrict__ ws, float* __restrict__ out) {
    __shared__ float rL[8], rD[8];
    int b = blockIdx.x;                 // 0..7
    int tid = threadIdx.x;              // 0..511
    float A = alpha[0], Bv = beta[0];

    float lsum = 0.f, dsum = 0.f;
    int t = tid;
    if (t < Tt) {
        #pragma unroll
        for (int nn = 0; nn < 2; ++nn) {
            int idx = (b * 2 + nn) * 512 + t;
            float4 m4 = *(const float4*)(ws + F_PM + (size_t)idx * 4);
            float4 l4 = *(const float4*)(ws + F_PL + (size_t)idx * 4);
            float m = m4.x, l = l4.x, nm;
            nm = fmaxf(m, m4.y); l = l * EXP2F(m - nm) + l4.y * EXP2F(m4.y - nm); m = nm;
            nm = fmaxf(m, m4.z); l = l * EXP2F(m - nm) + l4.z * EXP2F(m4.z - nm); m = nm;
            nm = fmaxf(m, m4.w); l = l * EXP2F(m - nm) + l4.w * EXP2F(m4.w - nm); m = nm;
            lsum += LN2 * (m + LOG2F(l));
        }
        const float4* P0 = (const float4*)(ws + F_DMP2 + ((size_t)(2 * b + 0) * 512 + t) * 8);
        const float4* P1 = (const float4*)(ws + F_DMP2 + ((size_t)(2 * b + 1) * 512 + t) * 8);
        float4 a0 = P0[0], a1 = P0[1];
        float4 b0 = P1[0], b1 = P1[1];
        float d00 = a0.x + a0.z + a1.x + a1.z;
        float d01 = a0.y + a0.w + a1.y + a1.w;
        float d10 = b0.x + b0.z + b1.x + b1.z;
        float d11 = b0.y + b0.w + b1.y + b1.w;
        float dm = fminf(d00 + d11, d01 + d10);
        dsum = -A * dm + Bv;
    }

    int lane = tid & 63, w = tid >> 6;
    #pragma unroll
    for (int off = 32; off > 0; off >>= 1) {
        lsum += __shfl_down(lsum, off, 64);
        dsum += __shfl_down(dsum, off, 64);
    }
    if (lane == 0) { rL[w] = lsum; rD[w] = dsum; }
    __syncthreads();
    if (tid == 0) {
        float L = 0.f, D = 0.f;
        #pragma unroll
        for (int wv = 0; wv < 8; ++wv) { L += rL[wv]; D += rD[wv]; }
        atomicAdd(&out[BN * Dd], -(D / (float)(Bb * Tt)) + L / (float)(BN * Tt));
    }
}

extern "C" void kernel_launch(void* const* d_in, const int* in_sizes, int n_in,
                              void* d_out, int out_size, void* d_ws, size_t ws_size,
                              hipStream_t stream) {
    const float* H     = (const float*)d_in[0];
    const int*   S     = (const int*)d_in[1];
    const float* E     = (const float*)d_in[2];
    const float* alpha = (const float*)d_in[3];
    const float* beta  = (const float*)d_in[4];
    float* out = (float*)d_out;
    float* ws  = (float*)d_ws;

    prep_all_kernel<<<1552, 256, 0, stream>>>(E, S, H, alpha, beta, ws, out);
    lse_mfma_kernel<<<dim3(BN, 8, 4), 256, 0, stream>>>(alpha, beta, ws);
    final_kernel<<<8, 512, 0, stream>>>(alpha, beta, ws, out);
}